// Round 1
// baseline (104.014 us; speedup 1.0000x reference)
//
#include <hip/hip_runtime.h>
#include <math.h>

#define IT 3
#define ROWS 144
#define NCOLS 576
#define ROW_DEG 6
#define NTHREADS 192
#define NWAVES 3

// Soft 4-level quantizer, collapsed for equally-spaced qk:
//   w_i ∝ exp(-(x-q_i)^2 * inv2e)  ∝  k_i * B^i,
//   B = exp(2*x*dq*inv2e), k_i = exp(-q_i^2*inv2e)  (x^2 term cancels in softmax).
// One v_exp + Horner(num)/Horner(den) + v_rcp instead of 4 exps + max-tree + div.
// s clamped to +/-30: beyond that the softmax is saturated to q0/q3 within 1e-6,
// and Horner keeps intermediates <= ~4e32 (no fp32 overflow; never forms B^3 alone).
__device__ __forceinline__ float quantize1(float x, float S,
                                           float K0, float K1, float K2, float K3,
                                           float KQ0, float KQ1, float KQ2, float KQ3) {
    float s = fminf(fmaxf(x * S, -30.0f), 30.0f);
    float B = __expf(s);
    float den = ((K3 * B + K2) * B + K1) * B + K0;
    float num = ((KQ3 * B + KQ2) * B + KQ1) * B + KQ0;
    return num * __builtin_amdgcn_rcpf(den);
}

__device__ __forceinline__ float signf(float x) {
    return (x > 0.0f) ? 1.0f : ((x < 0.0f) ? -1.0f : 0.0f);
}

// Single kernel: no workspace use (the 256 MiB d_ws re-poison fill was ~40.7 us
// of the 80.7 us timed window). Each block re-derives the 144x6 column lists
// from H via the ballot-compaction trick (ascending order -> matches jax top_k
// first-occurrence tie-break), ~331 KB of L2-resident reads per block.
__global__ __launch_bounds__(NTHREADS) void decode_kernel(
    const float* __restrict__ r, const float* __restrict__ H,
    const float* __restrict__ alpha, const float* __restrict__ beta,
    const float* __restrict__ eta, const float* __restrict__ qk,
    float* __restrict__ out)
{
    __shared__ __align__(16) float s_r[NCOLS];
    __shared__ __align__(16) float s_sumE[NCOLS];
    __shared__ int s_cols[ROWS * ROW_DEG];

    const int b   = blockIdx.x;
    const int tid = threadIdx.x;

    // Stage r (float4-coalesced).
    const float4* rb4 = reinterpret_cast<const float4*>(r + (size_t)b * NCOLS);
    float4* s_r4 = reinterpret_cast<float4*>(s_r);
    for (int j = tid; j < NCOLS / 4; j += NTHREADS) s_r4[j] = rb4[j];

    // Column extraction: each wave owns rows {wv, wv+3, ...}; per row, preload
    // all 9 coalesced 64-lane values (9 outstanding loads), then ballot+popc
    // prefix compacts nonzero column indices in ascending order into LDS.
    {
        const int wv = tid >> 6, lane = tid & 63;
        for (int rr = wv; rr < ROWS; rr += NWAVES) {
            float hv[9];
            #pragma unroll
            for (int i = 0; i < 9; ++i) hv[i] = H[rr * NCOLS + i * 64 + lane];
            int base = 0;
            #pragma unroll
            for (int i = 0; i < 9; ++i) {
                bool nz = hv[i] != 0.0f;
                unsigned long long mk = __ballot(nz);
                if (nz) {
                    int rank = base + __popcll(mk & ((1ull << lane) - 1ull));
                    if (rank < ROW_DEG) s_cols[rr * ROW_DEG + rank] = i * 64 + lane;
                }
                base += __popcll(mk);
            }
        }
    }

    // Hoist scalar params; per-iteration quantizer constants.
    const float q0 = qk[0], q1 = qk[1], q2 = qk[2], q3 = qk[3];
    const float dq = (q3 - q0) * (1.0f / 3.0f);  // equal spacing of qk
    float al[IT], be[IT], sc[IT];
    float k0[IT], k1[IT], k2[IT], k3[IT];
    #pragma unroll
    for (int t = 0; t < IT; ++t) {
        al[t] = alpha[t];
        be[t] = beta[t];
        float inv2e = 1.0f / (2.0f * eta[t] * eta[t] + 1e-12f);
        sc[t] = 2.0f * dq * inv2e;
        k0[t] = __expf(-q0 * q0 * inv2e);
        k1[t] = __expf(-q1 * q1 * inv2e);
        k2[t] = __expf(-q2 * q2 * inv2e);
        k3[t] = __expf(-q3 * q3 * inv2e);
    }

    const int row = tid;
    const bool active = row < ROWS;

    int   c[ROW_DEG];
    float m[ROW_DEG];
    float E[ROW_DEG];

    __syncthreads();  // s_r + s_cols ready
    if (active) {
        #pragma unroll
        for (int e = 0; e < ROW_DEG; ++e) {
            c[e] = s_cols[row * ROW_DEG + e];
            m[e] = s_r[c[e]];
        }
    }

    #pragma unroll
    for (int t = 0; t < IT; ++t) {
        __syncthreads();  // previous iter's s_sumE reads must finish before re-zero
        for (int j = tid; j < NCOLS; j += NTHREADS) s_sumE[j] = 0.0f;
        __syncthreads();

        const float A = al[t], Bt = be[t], S = sc[t];
        const float K0 = k0[t], K1 = k1[t], K2 = k2[t], K3 = k3[t];
        const float KQ0 = K0 * q0, KQ1 = K1 * q1, KQ2 = K2 * q2, KQ3 = K3 * q3;

        if (active) {
            // top-2 min of |m| + first-occurrence argmin, sign product
            float min1 = INFINITY, min2 = INFINITY;
            int idx = -1;
            float sp = 1.0f;
            #pragma unroll
            for (int e = 0; e < ROW_DEG; ++e) {
                float a = fabsf(m[e]);
                sp *= signf(m[e]);
                if (a < min1) { min2 = min1; min1 = a; idx = e; }
                else if (a < min2) { min2 = a; }
            }
            #pragma unroll
            for (int e = 0; e < ROW_DEG; ++e) {
                float eabs = (e == idx) ? min2 : min1;
                float v = A * sp * signf(m[e]) * fmaxf(0.0f, eabs - Bt);
                v = quantize1(v, S, K0, K1, K2, K3, KQ0, KQ1, KQ2, KQ3);
                E[e] = v;
                atomicAdd(&s_sumE[c[e]], v);  // avg col degree 1.5 -> no contention
            }
        }
        __syncthreads();

        if (t < IT - 1 && active) {
            #pragma unroll
            for (int e = 0; e < ROW_DEG; ++e) {
                float v = s_r[c[e]] + s_sumE[c[e]] - E[e];
                m[e] = quantize1(v, S, K0, K1, K2, K3, KQ0, KQ1, KQ2, KQ3);
            }
        }
    }

    // out = r + colsum(E_final); s_sumE holds exactly that after the last iter.
    float4* ob4 = reinterpret_cast<float4*>(out + (size_t)b * NCOLS);
    float4* s_s4 = reinterpret_cast<float4*>(s_sumE);
    for (int j = tid; j < NCOLS / 4; j += NTHREADS) {
        float4 rv = s_r4[j], sv = s_s4[j];
        float4 o;
        o.x = rv.x + sv.x; o.y = rv.y + sv.y;
        o.z = rv.z + sv.z; o.w = rv.w + sv.w;
        ob4[j] = o;
    }
}

extern "C" void kernel_launch(void* const* d_in, const int* in_sizes, int n_in,
                              void* d_out, int out_size, void* d_ws, size_t ws_size,
                              hipStream_t stream) {
    const float* r     = (const float*)d_in[0];
    const float* H     = (const float*)d_in[1];
    const float* alpha = (const float*)d_in[2];
    const float* beta  = (const float*)d_in[3];
    const float* eta   = (const float*)d_in[4];
    const float* qk    = (const float*)d_in[5];
    float* out = (float*)d_out;

    const int batch = in_sizes[0] / NCOLS;

    // No workspace use: avoids the per-iteration 256 MiB d_ws poison fill.
    (void)d_ws; (void)ws_size;

    hipLaunchKernelGGL(decode_kernel, dim3(batch), dim3(NTHREADS), 0, stream,
                       r, H, alpha, beta, eta, qk, out);
}

// Round 2
// 77.868 us; speedup vs baseline: 1.3358x; 1.3358x over previous
//
#include <hip/hip_runtime.h>
#include <math.h>

#define IT 3
#define ROWS 144
#define NCOLS 576
#define ROW_DEG 6

// Soft 4-level quantizer, collapsed for equally-spaced qk:
//   w_i ∝ exp(-(x-q_i)^2 * inv2e)  ∝  k_i * B^i,
//   B = exp(2*x*dq*inv2e), k_i = exp(-q_i^2*inv2e)  (x^2 term cancels in softmax).
// One v_exp + Horner(num)/Horner(den) + v_rcp instead of 4 exps + max-tree + div.
// s clamped to +/-30: beyond that the softmax saturates to q0/q3 within 1e-6,
// and Horner keeps intermediates <= ~4e32 (no fp32 overflow).
__device__ __forceinline__ float quantize1(float x, float S,
                                           float K0, float K1, float K2, float K3,
                                           float KQ0, float KQ1, float KQ2, float KQ3) {
    float s = fminf(fmaxf(x * S, -30.0f), 30.0f);
    float B = __expf(s);
    float den = ((K3 * B + K2) * B + K1) * B + K0;
    float num = ((KQ3 * B + KQ2) * B + KQ1) * B + KQ0;
    return num * __builtin_amdgcn_rcpf(den);
}

__device__ __forceinline__ float signf(float x) {
    return (x > 0.0f) ? 1.0f : ((x < 0.0f) ? -1.0f : 0.0f);
}

// One wave per row: 9 coalesced 64-lane loads cover 576 columns; ballot+popc
// prefix compacts nonzero column indices in ascending order (matches jax
// top_k first-occurrence tie-break downstream). Runs with row-parallel grid
// (144 blocks) so no wave ever serializes over rows. d_ws poison is
// unconditional in the harness (measured r0 vs r1), so using d_ws is free.
__global__ __launch_bounds__(64) void extract_cols_kernel(
    const float* __restrict__ H, int* __restrict__ cols)
{
    const int row  = blockIdx.x;
    const int lane = threadIdx.x;
    float hv[9];
    #pragma unroll
    for (int i = 0; i < 9; ++i) hv[i] = H[row * NCOLS + i * 64 + lane];
    int base = 0;
    #pragma unroll
    for (int i = 0; i < 9; ++i) {
        bool nz = hv[i] != 0.0f;
        unsigned long long mask = __ballot(nz);
        if (nz) {
            int rank = base + __popcll(mask & ((1ull << lane) - 1ull));
            if (rank < ROW_DEG) cols[row * ROW_DEG + rank] = i * 64 + lane;
        }
        base += __popcll(mask);
    }
}

// One WAVE per batch item (latency-bound regime: barriers are single-wave
// near-no-ops, and each lane carries 3 rows => 18 independent quantize chains
// of ILP). Lanes 0..63 own rows {lane, lane+64, lane+128<144}.
__global__ __launch_bounds__(64) void decode_kernel(
    const float* __restrict__ r, const int* __restrict__ cols,
    const float* __restrict__ alpha, const float* __restrict__ beta,
    const float* __restrict__ eta, const float* __restrict__ qk,
    float* __restrict__ out)
{
    __shared__ __align__(16) float s_r[NCOLS];
    __shared__ __align__(16) float s_sumE[NCOLS];

    const int b    = blockIdx.x;
    const int lane = threadIdx.x;

    // Issue param loads first (L2-hot after first blocks), overlap with r staging.
    const float q0 = qk[0], q1 = qk[1], q2 = qk[2], q3 = qk[3];

    // Stage r (float4-coalesced): 144 float4 over 64 lanes.
    const float4* rb4 = reinterpret_cast<const float4*>(r + (size_t)b * NCOLS);
    float4* s_r4 = reinterpret_cast<float4*>(s_r);
    #pragma unroll
    for (int p = 0; p < 3; ++p) {
        int j = lane + 64 * p;
        if (j < NCOLS / 4) s_r4[j] = rb4[j];
    }

    const float dq = (q3 - q0) * (1.0f / 3.0f);  // equal spacing of qk
    float al[IT], be[IT], sc[IT];
    float k0[IT], k1[IT], k2[IT], k3[IT];
    #pragma unroll
    for (int t = 0; t < IT; ++t) {
        al[t] = alpha[t];
        be[t] = beta[t];
        float inv2e = 1.0f / (2.0f * eta[t] * eta[t] + 1e-12f);
        sc[t] = 2.0f * dq * inv2e;
        k0[t] = __expf(-q0 * q0 * inv2e);
        k1[t] = __expf(-q1 * q1 * inv2e);
        k2[t] = __expf(-q2 * q2 * inv2e);
        k3[t] = __expf(-q3 * q3 * inv2e);
    }

    // 3 row slots per lane; slot 2 active only for lanes < ROWS - 128 = 16.
    const bool act2 = lane < (ROWS - 128);

    int   c[3][ROW_DEG];
    float m[3][ROW_DEG];
    float E[3][ROW_DEG];

    __syncthreads();  // single-wave barrier: just orders LDS writes vs reads

    #pragma unroll
    for (int p = 0; p < 3; ++p) {
        if (p == 2 && !act2) continue;
        const int row = lane + 64 * p;
        #pragma unroll
        for (int e = 0; e < ROW_DEG; ++e) {
            c[p][e] = cols[row * ROW_DEG + e];
            m[p][e] = s_r[c[p][e]];
        }
    }

    #pragma unroll
    for (int t = 0; t < IT; ++t) {
        __syncthreads();  // prior-iter s_sumE reads complete before re-zero
        #pragma unroll
        for (int p = 0; p < 9; ++p) s_sumE[lane + 64 * p] = 0.0f;
        __syncthreads();

        const float A = al[t], Bt = be[t], S = sc[t];
        const float K0 = k0[t], K1 = k1[t], K2 = k2[t], K3 = k3[t];
        const float KQ0 = K0 * q0, KQ1 = K1 * q1, KQ2 = K2 * q2, KQ3 = K3 * q3;

        #pragma unroll
        for (int p = 0; p < 3; ++p) {
            if (p == 2 && !act2) continue;
            // top-2 min of |m| + first-occurrence argmin, sign product
            float min1 = INFINITY, min2 = INFINITY;
            int idx = -1;
            float sp = 1.0f;
            #pragma unroll
            for (int e = 0; e < ROW_DEG; ++e) {
                float a = fabsf(m[p][e]);
                sp *= signf(m[p][e]);
                if (a < min1) { min2 = min1; min1 = a; idx = e; }
                else if (a < min2) { min2 = a; }
            }
            #pragma unroll
            for (int e = 0; e < ROW_DEG; ++e) {
                float eabs = (e == idx) ? min2 : min1;
                float v = A * sp * signf(m[p][e]) * fmaxf(0.0f, eabs - Bt);
                v = quantize1(v, S, K0, K1, K2, K3, KQ0, KQ1, KQ2, KQ3);
                E[p][e] = v;
                atomicAdd(&s_sumE[c[p][e]], v);  // avg col degree 1.5
            }
        }
        __syncthreads();

        if (t < IT - 1) {
            #pragma unroll
            for (int p = 0; p < 3; ++p) {
                if (p == 2 && !act2) continue;
                #pragma unroll
                for (int e = 0; e < ROW_DEG; ++e) {
                    float v = s_r[c[p][e]] + s_sumE[c[p][e]] - E[p][e];
                    m[p][e] = quantize1(v, S, K0, K1, K2, K3, KQ0, KQ1, KQ2, KQ3);
                }
            }
        }
    }

    // out = r + colsum(E_final); s_sumE holds exactly that after the last iter.
    float4* ob4 = reinterpret_cast<float4*>(out + (size_t)b * NCOLS);
    float4* s_s4 = reinterpret_cast<float4*>(s_sumE);
    #pragma unroll
    for (int p = 0; p < 3; ++p) {
        int j = lane + 64 * p;
        if (j < NCOLS / 4) {
            float4 rv = s_r4[j], sv = s_s4[j];
            float4 o;
            o.x = rv.x + sv.x; o.y = rv.y + sv.y;
            o.z = rv.z + sv.z; o.w = rv.w + sv.w;
            ob4[j] = o;
        }
    }
}

extern "C" void kernel_launch(void* const* d_in, const int* in_sizes, int n_in,
                              void* d_out, int out_size, void* d_ws, size_t ws_size,
                              hipStream_t stream) {
    const float* r     = (const float*)d_in[0];
    const float* H     = (const float*)d_in[1];
    const float* alpha = (const float*)d_in[2];
    const float* beta  = (const float*)d_in[3];
    const float* eta   = (const float*)d_in[4];
    const float* qk    = (const float*)d_in[5];
    float* out = (float*)d_out;

    int* cols = (int*)d_ws;  // ROWS*ROW_DEG ints = 3456 B (ws poison is unconditional)
    const int batch = in_sizes[0] / NCOLS;

    hipLaunchKernelGGL(extract_cols_kernel, dim3(ROWS), dim3(64), 0, stream,
                       H, cols);
    hipLaunchKernelGGL(decode_kernel, dim3(batch), dim3(64), 0, stream,
                       r, cols, alpha, beta, eta, qk, out);
}